// Round 1
// baseline (112.749 us; speedup 1.0000x reference)
//
#include <hip/hip_runtime.h>

#define UNITS 14336
#define IN_F 4096
#define PACKED 1024
#define CLIP_VAL 100.0f

typedef unsigned int uint32;
typedef unsigned short ushort16;

// MFMA fragment types (per cdna_hip_programming.md §3, compile-verified form)
using bf16x8 = __attribute__((ext_vector_type(8))) short;   // 8 bf16 = 4 VGPRs
using f32x4  = __attribute__((ext_vector_type(4))) float;   // 4 fp32 acc

// fp32 -> bf16 round-to-nearest-even
__device__ inline unsigned short f2bf(float f) {
    uint32 u = __float_as_uint(f);
    u += 0x7FFFu + ((u >> 16) & 1u);
    return (unsigned short)(u >> 16);
}

// Kernel 1: convert x [32][4096] fp32 -> bf16, swizzled into MFMA A-fragment order.
// ws granule t = ((s*2 + h)*64 + lane), each granule = 8 bf16 (16B):
//   element j of granule t corresponds to x[b][k], b = h*16 + (lane&15),
//   k = s*32 + (lane>>4)*8 + j.
__global__ __launch_bounds__(256) void convert_x_kernel(
    const float* __restrict__ x, uint4* __restrict__ ws) {
    int t = blockIdx.x * 256 + threadIdx.x;      // 0..16383
    int s = t >> 7;
    int h = (t >> 6) & 1;
    int lane = t & 63;
    int b = h * 16 + (lane & 15);
    int k = s * 32 + ((lane >> 4) << 3);
    const float4* src = (const float4*)(x + b * IN_F + k);
    float4 lo = src[0];
    float4 hi = src[1];
    uint4 o;
    o.x = (uint32)f2bf(lo.x) | ((uint32)f2bf(lo.y) << 16);
    o.y = (uint32)f2bf(lo.z) | ((uint32)f2bf(lo.w) << 16);
    o.z = (uint32)f2bf(hi.x) | ((uint32)f2bf(hi.y) << 16);
    o.w = (uint32)f2bf(hi.z) | ((uint32)f2bf(hi.w) << 16);
    ws[t] = o;
}

// SWAR unpack: one packed byte (int32 value 0..255, 4 crumbs little-endian)
// -> two uint32, each holding 2 bf16: r0 = {bf(c0), bf(c1)}, r1 = {bf(c2), bf(c3)}.
// crumb->bf16: 0->0x0000, 1->0x3F80 (+1), 2->0xBF80 (-1), 3->0x8000 (-0.0, harmless in MAC)
__device__ inline void unpack_byte(int v, uint32& r0, uint32& r1) {
    uint32 t0 = ((uint32)v & 3u) | (((uint32)v & 0xCu) << 14);       // c0 @ [1:0], c1 @ [17:16]
    uint32 t1 = (((uint32)v >> 4) & 3u) | (((uint32)v & 0xC0u) << 10); // c2, c3
    uint32 s0 = t0 >> 1;
    uint32 s1 = t1 >> 1;
    uint32 nz0 = (t0 ^ s0) & 0x00010001u;
    uint32 nz1 = (t1 ^ s1) & 0x00010001u;
    r0 = nz0 * 0x3F80u + ((s0 & 0x00010001u) << 15);
    r1 = nz1 * 0x3F80u + ((s1 & 0x00010001u) << 15);
}

__device__ inline float clipf(float y) {
    return fminf(fmaxf(y, -CLIP_VAL), CLIP_VAL);
}

// Kernel 2: main MFMA GEMM.
// Grid: 896 blocks (one per 16-unit tile), 256 threads = 4 waves.
// Wave w handles K-quarter [w*1024, w*1024+1024) = 32 K-steps of 32.
// Per K-step: 2 MFMAs (batches 0-15 and 16-31) with one B fragment.
__global__ __launch_bounds__(256) void ternary_mm_kernel(
    const uint4* __restrict__ xw,     // swizzled bf16 x
    const int*   __restrict__ pw,     // [UNITS][PACKED] packed bytes as int32
    const float* __restrict__ scale,
    const float* __restrict__ bias,
    float*       __restrict__ out) {
    __shared__ float4 red[4][128];    // [wave][frag*64 + lane]

    const int tid  = threadIdx.x;
    const int wid  = tid >> 6;
    const int lane = tid & 63;
    const int u0   = blockIdx.x << 4;
    const int urow = u0 + (lane & 15);
    const int q    = lane >> 4;          // quad 0..3

    f32x4 acc0 = {0.f, 0.f, 0.f, 0.f};
    f32x4 acc1 = {0.f, 0.f, 0.f, 0.f};

    const int s_begin = wid << 5;                          // first K-step index
    const int*   pwbase = pw + urow * PACKED + (q << 1) + (s_begin << 3);
    const uint4* xbase  = xw + (s_begin << 1) * 64 + lane;

    #pragma unroll 4
    for (int i = 0; i < 32; ++i) {
        uint4 a0u = xbase[i * 128];        // h=0 (batches 0-15)
        uint4 a1u = xbase[i * 128 + 64];   // h=1 (batches 16-31)
        int2 w2 = *(const int2*)(pwbase + i * 8);

        uint4 bu;
        unpack_byte(w2.x, bu.x, bu.y);     // j = 0..3
        unpack_byte(w2.y, bu.z, bu.w);     // j = 4..7
        bf16x8 bfrag = __builtin_bit_cast(bf16x8, bu);

        acc0 = __builtin_amdgcn_mfma_f32_16x16x32_bf16(
            __builtin_bit_cast(bf16x8, a0u), bfrag, acc0, 0, 0, 0);
        acc1 = __builtin_amdgcn_mfma_f32_16x16x32_bf16(
            __builtin_bit_cast(bf16x8, a1u), bfrag, acc1, 0, 0, 0);
    }

    red[wid][lane]      = make_float4(acc0[0], acc0[1], acc0[2], acc0[3]);
    red[wid][64 + lane] = make_float4(acc1[0], acc1[1], acc1[2], acc1[3]);
    __syncthreads();

    // Reduce 4 K-partials + epilogue. 128 active threads, one per (frag, lane).
    if (tid < 128) {
        const int f = tid >> 6;      // 0: batches 0-15, 1: batches 16-31
        const int l = tid & 63;
        float4 v0 = red[0][f * 64 + l];
        float4 v1 = red[1][f * 64 + l];
        float4 v2 = red[2][f * 64 + l];
        float4 v3 = red[3][f * 64 + l];
        float vx = v0.x + v1.x + v2.x + v3.x;
        float vy = v0.y + v1.y + v2.y + v3.y;
        float vz = v0.z + v1.z + v2.z + v3.z;
        float vw = v0.w + v1.w + v2.w + v3.w;

        const int u  = u0 + (l & 15);
        const int b0 = f * 16 + ((l >> 4) << 2);   // row = (lane>>4)*4 + reg
        const float sc = scale[u];
        const float bi = bias[u];
        float* o = out + (size_t)b0 * UNITS + u;
        o[0 * UNITS] = clipf(vx * sc + bi);
        o[1 * UNITS] = clipf(vy * sc + bi);
        o[2 * UNITS] = clipf(vz * sc + bi);
        o[3 * UNITS] = clipf(vw * sc + bi);
    }
}

extern "C" void kernel_launch(void* const* d_in, const int* in_sizes, int n_in,
                              void* d_out, int out_size, void* d_ws, size_t ws_size,
                              hipStream_t stream) {
    const float* x     = (const float*)d_in[0];
    const int*   pw    = (const int*)d_in[1];
    const float* scale = (const float*)d_in[2];
    const float* bias  = (const float*)d_in[3];
    float* out = (float*)d_out;

    // ws usage: 32*4096 bf16 = 256 KB swizzled x
    uint4* xw = (uint4*)d_ws;

    convert_x_kernel<<<64, 256, 0, stream>>>(x, xw);
    ternary_mm_kernel<<<UNITS / 16, 256, 0, stream>>>(xw, pw, scale, bias, out);
}

// Round 2
// 110.622 us; speedup vs baseline: 1.0192x; 1.0192x over previous
//
#include <hip/hip_runtime.h>

#define UNITS 14336
#define IN_F 4096
#define PACKED 1024
#define CLIP_VAL 100.0f

typedef unsigned int uint32;

using bf16x8 = __attribute__((ext_vector_type(8))) short;   // 8 bf16 = 4 VGPRs
using f32x4  = __attribute__((ext_vector_type(4))) float;   // 4 fp32 acc

// fp32 -> bf16 round-to-nearest-even
__device__ inline unsigned short f2bf(float f) {
    uint32 u = __float_as_uint(f);
    u += 0x7FFFu + ((u >> 16) & 1u);
    return (unsigned short)(u >> 16);
}

// Kernel 1: convert x [32][4096] fp32 -> bf16, swizzled into MFMA A-fragment order.
// ws granule t = ((s*2 + h)*64 + lane), each granule = 8 bf16 (16B):
//   element j of granule t corresponds to x[b][k], b = h*16 + (lane&15),
//   k = s*32 + (lane>>4)*8 + j.
__global__ __launch_bounds__(256) void convert_x_kernel(
    const float* __restrict__ x, uint4* __restrict__ ws) {
    int t = blockIdx.x * 256 + threadIdx.x;      // 0..16383
    int s = t >> 7;
    int h = (t >> 6) & 1;
    int lane = t & 63;
    int b = h * 16 + (lane & 15);
    int k = s * 32 + ((lane >> 4) << 3);
    const float4* src = (const float4*)(x + b * IN_F + k);
    float4 lo = src[0];
    float4 hi = src[1];
    uint4 o;
    o.x = (uint32)f2bf(lo.x) | ((uint32)f2bf(lo.y) << 16);
    o.y = (uint32)f2bf(lo.z) | ((uint32)f2bf(lo.w) << 16);
    o.z = (uint32)f2bf(hi.x) | ((uint32)f2bf(hi.y) << 16);
    o.w = (uint32)f2bf(hi.z) | ((uint32)f2bf(hi.w) << 16);
    ws[t] = o;
}

// SWAR unpack: one packed byte (int32 value 0..255, 4 crumbs little-endian)
// -> two uint32, each holding 2 bf16: r0 = {bf(c0), bf(c1)}, r1 = {bf(c2), bf(c3)}.
// crumb->bf16: 0->0x0000, 1->0x3F80 (+1), 2->0xBF80 (-1), 3->0x8000 (-0.0, harmless in MAC)
__device__ inline void unpack_byte(int v, uint32& r0, uint32& r1) {
    uint32 t0 = ((uint32)v & 3u) | (((uint32)v & 0xCu) << 14);         // c0 @ [1:0], c1 @ [17:16]
    uint32 t1 = (((uint32)v >> 4) & 3u) | (((uint32)v & 0xC0u) << 10); // c2, c3
    uint32 s0 = t0 >> 1;
    uint32 s1 = t1 >> 1;
    uint32 nz0 = (t0 ^ s0) & 0x00010001u;
    uint32 nz1 = (t1 ^ s1) & 0x00010001u;
    r0 = nz0 * 0x3F80u + ((s0 & 0x00010001u) << 15);
    r1 = nz1 * 0x3F80u + ((s1 & 0x00010001u) << 15);
}

__device__ inline float clipf(float y) {
    return fminf(fmaxf(y, -CLIP_VAL), CLIP_VAL);
}

// Kernel 2: main MFMA GEMM, v2.
// Grid: 448 blocks x 512 threads (8 waves). Block tile: 32 units x 32 batches.
// Wave wid owns K-slice [wid*512, wid*512+512) = 16 K-steps of 32.
// Per K-step: 2 weight int2 loads (unit groups g0/g1) + 2 x-frag loads
// (batch halves h0/h1) -> 4 MFMAs. LDS reduce over the 8 K-partials + epilogue.
__global__ __launch_bounds__(512) void ternary_mm_kernel(
    const uint4* __restrict__ xw,     // swizzled bf16 x
    const int*   __restrict__ pw,     // [UNITS][PACKED] packed bytes as int32
    const float* __restrict__ scale,
    const float* __restrict__ bias,
    float*       __restrict__ out) {
    __shared__ f32x4 red[8][4][64];   // [wave][frag g*2+h][lane] = 32 KB

    const int tid  = threadIdx.x;
    const int wid  = tid >> 6;           // 0..7 = K-split index
    const int lane = tid & 63;
    const int q    = lane >> 4;          // quad 0..3
    const int n    = lane & 15;
    const int u0   = blockIdx.x << 5;    // 32 units per block

    f32x4 acc00 = {0.f,0.f,0.f,0.f};     // units g0, batches h0
    f32x4 acc10 = {0.f,0.f,0.f,0.f};     // units g0, batches h1
    f32x4 acc01 = {0.f,0.f,0.f,0.f};     // units g1, batches h0
    f32x4 acc11 = {0.f,0.f,0.f,0.f};     // units g1, batches h1

    const int s_begin = wid << 4;        // first K-step (of 128 total)
    const int* pA = pw + (size_t)(u0 + n)      * PACKED + (q << 1) + (s_begin << 3);
    const int* pB = pw + (size_t)(u0 + 16 + n) * PACKED + (q << 1) + (s_begin << 3);
    const uint4* xb = xw + (s_begin << 7) + lane;   // granule (s*2+h)*64 + lane

    #pragma unroll 4
    for (int i = 0; i < 16; ++i) {
        uint4 a0u = xb[i * 128];          // h=0 (batches 0-15)
        uint4 a1u = xb[i * 128 + 64];     // h=1 (batches 16-31)
        int2 wA = *(const int2*)(pA + i * 8);
        int2 wB = *(const int2*)(pB + i * 8);

        uint4 bA, bB;
        unpack_byte(wA.x, bA.x, bA.y);    // j = 0..3
        unpack_byte(wA.y, bA.z, bA.w);    // j = 4..7
        unpack_byte(wB.x, bB.x, bB.y);
        unpack_byte(wB.y, bB.z, bB.w);
        bf16x8 fA = __builtin_bit_cast(bf16x8, bA);
        bf16x8 fB = __builtin_bit_cast(bf16x8, bB);
        bf16x8 x0 = __builtin_bit_cast(bf16x8, a0u);
        bf16x8 x1 = __builtin_bit_cast(bf16x8, a1u);

        acc00 = __builtin_amdgcn_mfma_f32_16x16x32_bf16(x0, fA, acc00, 0, 0, 0);
        acc10 = __builtin_amdgcn_mfma_f32_16x16x32_bf16(x1, fA, acc10, 0, 0, 0);
        acc01 = __builtin_amdgcn_mfma_f32_16x16x32_bf16(x0, fB, acc01, 0, 0, 0);
        acc11 = __builtin_amdgcn_mfma_f32_16x16x32_bf16(x1, fB, acc11, 0, 0, 0);
    }

    red[wid][0][lane] = acc00;   // f = g*2 + h
    red[wid][1][lane] = acc10;
    red[wid][2][lane] = acc01;
    red[wid][3][lane] = acc11;
    __syncthreads();

    // Reduce 8 K-partials + epilogue. 256 active threads, one per (frag, lane).
    if (tid < 256) {
        const int f = tid >> 6;          // g = f>>1, h = f&1
        const int l = tid & 63;
        f32x4 s = red[0][f][l];
        #pragma unroll
        for (int w = 1; w < 8; ++w) {
            f32x4 v = red[w][f][l];
            s[0] += v[0]; s[1] += v[1]; s[2] += v[2]; s[3] += v[3];
        }
        const int g = f >> 1;
        const int h = f & 1;
        const int u  = u0 + g * 16 + (l & 15);
        const int b0 = h * 16 + ((l >> 4) << 2);   // row = (lane>>4)*4 + reg
        const float sc = scale[u];
        const float bi = bias[u];
        float* o = out + (size_t)b0 * UNITS + u;
        o[0 * UNITS] = clipf(s[0] * sc + bi);
        o[1 * UNITS] = clipf(s[1] * sc + bi);
        o[2 * UNITS] = clipf(s[2] * sc + bi);
        o[3 * UNITS] = clipf(s[3] * sc + bi);
    }
}

extern "C" void kernel_launch(void* const* d_in, const int* in_sizes, int n_in,
                              void* d_out, int out_size, void* d_ws, size_t ws_size,
                              hipStream_t stream) {
    const float* x     = (const float*)d_in[0];
    const int*   pw    = (const int*)d_in[1];
    const float* scale = (const float*)d_in[2];
    const float* bias  = (const float*)d_in[3];
    float* out = (float*)d_out;

    // ws usage: 32*4096 bf16 = 256 KB swizzled x
    uint4* xw = (uint4*)d_ws;

    convert_x_kernel<<<64, 256, 0, stream>>>(x, xw);
    ternary_mm_kernel<<<UNITS / 32, 512, 0, stream>>>(xw, pw, scale, bias, out);
}